// Round 3
// baseline (698.487 us; speedup 1.0000x reference)
//
#include <hip/hip_runtime.h>

// ---------------------------------------------------------------------------
// Tensor_CSPNet forward, restructured:
//   out[b,o] = sum_h <G[o,h], log(V_h^T X[b,h] V_h + D_h)> + const[o]
// ReEig stages are provably no-ops (all eigenvalues >= 0.5 >> 1e-4).
// Eigensolve: one-sided Hestenes Jacobi, pair-per-lane in registers,
// 16-lane groups (11 active), DPP circle-method migration.
// R16: prep Jacobi(bn,rm) -> block-parallel coupled Newton-Schulz (-13us).
// R17: prep G-pass coalesced (-9us). Prep now ~20us by model.
// R18: main occupancy fix. Counters: VALUBusy 71%, Occupancy 25% =
// 2 waves/SIMD -- VALU-issue-bound with nothing to hide serial chains
// (transcendental rotation math, DPP migration, dot chains). Cause:
// 64-thread (1-wave) workgroups; CP keeps only ~8 wg/CU resident.
// Fix: 4 waves/block (256 thr), grid 3456->864 (=27*32; identical
// per-wave work, h still wave-uniform), __launch_bounds__(256,8) ->
// up to 32 waves/CU. R14 lesson: missing parallelism was TLP not ILP.
// ---------------------------------------------------------------------------

#define WS_CONST 484                     // 4     : fc_w@conv_b + fc_b
#define WS_VT    512                     // 27*484: Vt[h][j][k] = V_h[k][j]
#define WS_V     (512 + 13068)           // 27*528: V[h][k][j], rows padded to 24
#define WS_D     (13580 + 14256)         // 27*484: D_h row-major (sym)
#define WS_G     (27836 + 13068)         // 4*27*528: G[o][h], rows padded to 24
#define G_STRIDE 528
#define V_STRIDE 528

typedef float v2f __attribute__((ext_vector_type(2)));

static __device__ __forceinline__ float dpp_shl1(float x) { // lane m <- lane m+1 (within 16-row)
  return __int_as_float(__builtin_amdgcn_mov_dpp(__float_as_int(x), 0x101, 0xf, 0xf, true));
}
static __device__ __forceinline__ float dpp_shr1(float x) { // lane m <- lane m-1 (within 16-row)
  return __int_as_float(__builtin_amdgcn_mov_dpp(__float_as_int(x), 0x111, 0xf, 0xf, true));
}

// one-sided Jacobi sweeps on column pairs held in registers (16-lane groups,
// lanes 0..10 active). Per-matrix convergence: offF2 = sum over the sweep's
// 231 pair-tests of d^2; exit at sweep s>=minsweep if previous sweep had
// offF2 <= eps2 * sum(lambda_i^2) for ALL 4 matrices in the wave.
static __device__ __forceinline__ void jacobi_sweeps(v2f wl[11], v2f wr[11],
                                                     bool is0, bool is10, bool inert,
                                                     int minsweep, float eps2) {
  int okprev = 0;
  #pragma unroll 1
  for (int sweep = 0; sweep < 5; ++sweep) {
    if (sweep >= minsweep && __all(okprev)) break;
    // fresh norms each sweep
    v2f na = (v2f)(0.f), nb = (v2f)(0.f);
    #pragma unroll
    for (int i = 0; i < 11; ++i) { na += wl[i]*wl[i]; nb += wr[i]*wr[i]; }
    float nL = na.x + na.y, nR = nb.x + nb.y;
    // Q = sum lambda_i^4 over the group's 22 columns (inert lanes gated out)
    float q = inert ? 0.f : (nL*nL + nR*nR);
    q += __shfl_xor(q, 1, 16);
    q += __shfl_xor(q, 2, 16);
    q += __shfl_xor(q, 4, 16);
    q += __shfl_xor(q, 8, 16);
    float dacc = 0.f;
    #pragma unroll 1
    for (int r = 0; r < 21; ++r) {
      v2f da = (v2f)(0.f), db = (v2f)(0.f);
      #pragma unroll
      for (int i = 0; i < 10; i += 2) { da += wl[i]*wr[i]; db += wl[i+1]*wr[i+1]; }
      da += wl[10]*wr[10];
      float d = (da.x + da.y) + (db.x + db.y);
      dacc += d*d;
      // R9 rotation math (measured fastest): tau chain
      float ad  = fabsf(d);
      float tau = (nR - nL)*0.5f*__builtin_amdgcn_rcpf(d);
      float sq  = sqrtf(1.0f + tau*tau);
      float t   = copysignf(__builtin_amdgcn_rcpf(fabsf(tau) + sq), tau);
      float c   = __builtin_amdgcn_rsqf(1.0f + t*t);
      float s   = t*c;
      bool tiny = (ad < 1e-28f);
      c = tiny ? 1.0f : c;
      s = tiny ? 0.0f : s;
      float cc = c*c, ss = s*s, cs2 = 2.0f*c*s;
      float nLn = cc*nL - cs2*d + ss*nR;
      float nRn = ss*nL + cs2*d + cc*nR;
      v2f cv = (v2f)(c), sv = (v2f)(s);
      #pragma unroll
      for (int i = 0; i < 11; ++i) {
        v2f nl = cv*wl[i] - sv*wr[i];
        v2f nr = sv*wl[i] + cv*wr[i];
        float tlx = dpp_shl1(nl.x), tly = dpp_shl1(nl.y);
        float trx = dpp_shr1(nr.x), trY = dpp_shr1(nr.y);
        wl[i].x = is0 ? nl.x : (is10 ? nr.x : tlx);
        wl[i].y = is0 ? nl.y : (is10 ? nr.y : tly);
        wr[i].x = is0 ? tlx : trx;
        wr[i].y = is0 ? tly : trY;
      }
      {
        float tl = dpp_shl1(nLn), tr = dpp_shr1(nRn);
        nL = is0 ? nLn : (is10 ? nRn : tl);
        nR = is0 ? tl : tr;
      }
    }
    float ds = inert ? 0.f : dacc;     // gate junk/NaN AFTER accumulation
    ds += __shfl_xor(ds, 1, 16);
    ds += __shfl_xor(ds, 2, 16);
    ds += __shfl_xor(ds, 4, 16);
    ds += __shfl_xor(ds, 8, 16);
    okprev = (ds <= eps2*q);
  }
}

// ---------------- prep: NS(bn,rm) -> S -> per-h Vt, V, D, G ----------------
// Coupled Newton-Schulz (all 256 threads, LDS matmuls):
//   A' = A/||A||_F ; Y0=A', Z0=I
//   T = 3I - Z@Y ; Y <- 0.5*Y@T ; Z <- 0.5*T@Z     (K=11 iterations)
//   Y -> A'^{1/2}, Z -> A'^{-1/2}
// S = rm^{-1/2} @ bn^{1/2} = sqrt(c_bn/c_rm) * Z_rm @ Y_bn.
__global__ void prep_kernel(const float* __restrict__ rm, const float* __restrict__ bn,
                            const float* __restrict__ W1, const float* __restrict__ W2,
                            const float* __restrict__ conv_w, const float* __restrict__ fc_w,
                            const float* __restrict__ conv_b, const float* __restrict__ fc_b,
                            float* __restrict__ ws, float* __restrict__ out) {
  __shared__ float sW1[1024] __attribute__((aligned(16)));
  __shared__ float sW2[704]  __attribute__((aligned(16)));
  __shared__ float sY[2][2][484] __attribute__((aligned(16)));  // [mat][buf][..]
  __shared__ float sZ[2][2][484] __attribute__((aligned(16)));
  __shared__ float sT[2][484]    __attribute__((aligned(16)));
  __shared__ float sS[484]  __attribute__((aligned(16)));
  __shared__ float sU[704]  __attribute__((aligned(16)));
  __shared__ float sE[220]  __attribute__((aligned(16)));
  __shared__ float sG[1936] __attribute__((aligned(16)));
  __shared__ float sC[2];
  const int tid = threadIdx.x, h = blockIdx.x;

  if (h == 0)  // zero the atomic-add target (replaces memset dispatch)
    for (int idx = tid; idx < 2048; idx += 256) out[idx] = 0.f;

  // phase A: waves 0/1 compute Frobenius norms of bn/rm; waves 2/3 stage W1,W2
  const int wv = tid >> 6, ln = tid & 63;
  if (wv < 2) {
    const float* src = wv ? rm : bn;
    float s = 0.f;
    for (int i = ln; i < 484; i += 64) { float v = src[i]; s += v*v; }
    s += __shfl_xor(s, 1);  s += __shfl_xor(s, 2);  s += __shfl_xor(s, 4);
    s += __shfl_xor(s, 8);  s += __shfl_xor(s, 16); s += __shfl_xor(s, 32);
    if (ln == 0) sC[wv] = sqrtf(s);
  } else {
    const int t = tid - 128;
    for (int i = t; i < 1024; i += 128) sW1[i] = W1[h*1024 + i];
    for (int i = t; i < 704;  i += 128) sW2[i] = W2[h*704 + i];
  }
  __syncthreads();

  // phase B: init Y = A/c, Z = I for both matrices
  {
    const float ic0 = 1.0f/sC[0], ic1 = 1.0f/sC[1];
    for (int idx = tid; idx < 484; idx += 256) {
      const int i = idx/22, j = idx - 22*i;
      const float e = (i == j) ? 1.f : 0.f;
      sY[0][0][idx] = bn[idx]*ic0;  sZ[0][0][idx] = e;
      sY[1][0][idx] = rm[idx]*ic1;  sZ[1][0][idx] = e;
    }
  }
  __syncthreads();

  // phase C: K=11 coupled NS iterations (v2f column pairs: 22 rows x 11 pairs)
  int cur = 0;
  #pragma unroll 1
  for (int it = 0; it < 11; ++it) {
    // T = 3I - Z@Y (both matrices: 484 v2f elements)
    for (int idx = tid; idx < 484; idx += 256) {
      const int mt = (idx >= 242), r = idx - mt*242, i = r/11, jp = r - 11*i;
      const float* Zc = sZ[mt][cur];
      const float* Yc = sY[mt][cur];
      v2f acc = (v2f)(0.f);
      #pragma unroll
      for (int k = 0; k < 22; ++k)
        acc += *(const v2f*)(Yc + k*22 + 2*jp) * Zc[i*22 + k];
      v2f tv;
      tv.x = ((2*jp     == i) ? 3.f : 0.f) - acc.x;
      tv.y = ((2*jp + 1 == i) ? 3.f : 0.f) - acc.y;
      *(v2f*)(sT[mt] + i*22 + 2*jp) = tv;
    }
    __syncthreads();
    // Ynew = 0.5*Y@T ; Znew = 0.5*T@Z  (968 v2f elements)
    for (int idx = tid; idx < 968; idx += 256) {
      const int sel = idx/242, r = idx - 242*sel, i = r/11, jp = r - 11*i;
      const int mt = sel >> 1; const bool isZ = sel & 1;
      const float* A = isZ ? sT[mt] : sY[mt][cur];
      const float* B = isZ ? sZ[mt][cur] : sT[mt];
      v2f acc = (v2f)(0.f);
      #pragma unroll
      for (int k = 0; k < 22; ++k)
        acc += *(const v2f*)(B + k*22 + 2*jp) * A[i*22 + k];
      *(v2f*)((isZ ? sZ[mt][cur^1] : sY[mt][cur^1]) + i*22 + 2*jp) = 0.5f*acc;
    }
    __syncthreads();
    cur ^= 1;   // data now lives in buffer 'cur'
  }

  // phase D: S = sqrt(c_bn/c_rm)*Z_rm@Y_bn ; U = W1@W2 ; raw G (coalesced)
  {
    const float scale = sqrtf(sC[0]/sC[1]);
    const float* Zrm = sZ[1][cur];
    const float* Ybn = sY[0][cur];
    for (int idx = tid; idx < 484; idx += 256) {
      const int i = idx/22, j = idx - 22*i;
      float s = 0.f;
      for (int k = 0; k < 22; ++k) s += Zrm[i*22+k]*Ybn[k*22+j];
      sS[idx] = scale*s;
    }
  }
  for (int idx = tid; idx < 704; idx += 256) {
    const int n = idx/22, j = idx - 22*n;
    float s = 0.f;
    for (int k = 0; k < 32; ++k) s += sW1[n*32+k]*sW2[k*22+j];
    sU[idx] = s;
  }
  // raw G, coalesced: thread t owns v2f element r = 2t,2t+1 of all 4 outputs.
  // 48 in-flight strided v2f loads (lanes contiguous per c), 4x register
  // reuse across o; fc_w indices are wave-uniform literals -> s_loads.
  if (tid < 242) {
    const int wi = h/9, bi = h - 9*wi;
    const float* base = conv_w + wi*4356 + bi*484 + 2*tid;
    v2f a0 = (v2f)(0.f), a1 = (v2f)(0.f), a2 = (v2f)(0.f), a3 = (v2f)(0.f);
    #pragma unroll
    for (int c = 0; c < 48; ++c) {
      const v2f wv2 = *(const v2f*)(base + c*13068);
      a0 += wv2*fc_w[c];
      a1 += wv2*fc_w[48+c];
      a2 += wv2*fc_w[96+c];
      a3 += wv2*fc_w[144+c];
    }
    *(v2f*)(sG +        2*tid) = a0;
    *(v2f*)(sG +  484 + 2*tid) = a1;
    *(v2f*)(sG +  968 + 2*tid) = a2;
    *(v2f*)(sG + 1452 + 2*tid) = a3;
  }
  __syncthreads();

  // V = U_top @ S: write transposed (Vt, packed) and row-major (stride 24)
  for (int idx = tid; idx < 484; idx += 256) {
    const int k = idx/22, j = idx - 22*k;
    float s = 0.f;
    for (int l = 0; l < 22; ++l) s += sU[k*22+l]*sS[l*22+j];
    ws[WS_VT + h*484 + j*22 + k] = s;
    ws[WS_V  + h*V_STRIDE + k*24 + j] = s;
  }
  // E = U_bot @ S (10x22)
  for (int idx = tid; idx < 220; idx += 256) {
    const int e = idx/22, j = idx - 22*e;
    float s = 0.f;
    for (int l = 0; l < 22; ++l) s += sU[(22+e)*22+l]*sS[l*22+j];
    sE[idx] = s;
  }
  __syncthreads();
  // D = E^T E (22x22, symmetric)
  for (int idx = tid; idx < 484; idx += 256) {
    const int i = idx/22, j = idx - 22*i;
    float s = 0.f;
    for (int e = 0; e < 10; ++e) s += sE[e*22+i]*sE[e*22+j];
    ws[WS_D + h*484 + idx] = s;
  }
  // G symmetrized into padded layout
  for (int idx = tid; idx < 1936; idx += 256) {
    const int o = idx/484, r = idx - 484*o, i = r/22, j = r - 22*i;
    const float v = 0.5f*(sG[o*484 + i*22 + j] + sG[o*484 + j*22 + i]);
    ws[WS_G + (o*27+h)*G_STRIDE + i*24 + j] = v;
  }
  if (h == 0 && tid < 4) {
    float s = 0.f;
    for (int c = 0; c < 48; ++c) s += fc_w[tid*48+c]*conv_b[c];
    ws[WS_CONST + tid] = s + fc_b[tid];
  }
}

// ---------------- main: P4 build + one-sided Jacobi + projection -----------
// 4 waves/block (256 thr); each wave = 4 matrices, identical to the old
// 1-wave blocks via gw = blockIdx*4 + wid. h wave-uniform -> V/D/G base
// pointers uniform -> scalar loads. Zero LDS; up to 8 blocks/CU (32 waves).
__global__ void __launch_bounds__(256, 8) main_kernel(const float* __restrict__ x,
                                                      const float* __restrict__ ws,
                                                      float* __restrict__ out) {
  const int lane = threadIdx.x & 63;
  const int wid  = threadIdx.x >> 6;
  const int gw   = blockIdx.x*4 + wid;       // global wave id, 0..3455
  const int g = lane >> 4, m = lane & 15;
  const int mm = (m < 10) ? m : 10;          // lanes 11..15 mirror pair 10 (inert)
  const int h  = gw % 27;                    // wave-uniform
  const int b  = (gw/27)*4 + g;
  const int id = b*27 + h;                   // matrix index in x

  // V column pair 2mm, 2mm+1 (rows 2mm,2mm+1 of Vt; 44 contiguous floats)
  v2f vl[11], vrr[11];
  {
    const v2f* vb = (const v2f*)(ws + WS_VT + h*484 + mm*44);
    #pragma unroll
    for (int j = 0; j < 11; ++j) { vl[j] = vb[j]; vrr[j] = vb[11+j]; }
  }
  // init w = D rows 2mm, 2mm+1 (columns of symmetric D)
  v2f wl[11], wr[11];
  {
    const v2f* d2 = (const v2f*)(ws + WS_D + h*484 + mm*44);
    #pragma unroll
    for (int j = 0; j < 11; ++j) { wl[j] = d2[j]; wr[j] = d2[11+j]; }
  }
  // streamed build: for each row k, t_k = <Xrow_k, v>, then w += V[k][:] * t_k
  {
    const v2f* X2 = (const v2f*)(x + (size_t)id * 484);
    const float* Vrow = ws + WS_V + h*V_STRIDE;
    #pragma unroll 2
    for (int k = 0; k < 22; ++k) {
      v2f aL = (v2f)(0.f), aR = (v2f)(0.f);
      #pragma unroll
      for (int c = 0; c < 11; ++c) {
        v2f xv = X2[11*k + c];
        aL += xv*vl[c];
        aR += xv*vrr[c];
      }
      float tLk = aL.x + aL.y, tRk = aR.x + aR.y;
      const v2f* vk = (const v2f*)(Vrow + k*24);
      #pragma unroll
      for (int j = 0; j < 11; ++j) {
        v2f q = vk[j];
        wl[j] += q*tLk;
        wr[j] += q*tRk;
      }
    }
  }

  jacobi_sweeps(wl, wr, (m == 0), (m == 10), (m > 10), 2, 1e-4f);

  // log-eig coefficients: L = sum_j (log lam_j / lam_j^2) w_j w_j^T, lam^2 = ||w||^2
  float nL, nR;
  {
    v2f na = (v2f)(0.f), nb = (v2f)(0.f);
    #pragma unroll
    for (int i = 0; i < 11; ++i) { na += wl[i]*wl[i]; nb += wr[i]*wr[i]; }
    nL = na.x + na.y; nR = nb.x + nb.y;
  }
  const float HALF_LN2 = 0.34657359f;        // 0.5*ln(2)
  float coefL = HALF_LN2*log2f(fmaxf(nL, 1e-8f))*__builtin_amdgcn_rcpf(nL);
  float coefR = HALF_LN2*log2f(fmaxf(nR, 1e-8f))*__builtin_amdgcn_rcpf(nR);

  // projection: out[b,o] += sum_cols coef * (w^T G[o,h] w)
  #pragma unroll 1
  for (int o = 0; o < 4; ++o) {
    const float* Gptr = ws + WS_G + (o*27+h)*G_STRIDE;
    float qL = 0.f, qR = 0.f;
    #pragma unroll
    for (int k = 0; k < 22; ++k) {
      const v2f* g2 = (const v2f*)(Gptr + k*24);
      v2f sa = (v2f)(0.f), ra = (v2f)(0.f);
      #pragma unroll
      for (int j = 0; j < 11; ++j) {
        v2f q = g2[j];
        sa += q*wl[j];
        ra += q*wr[j];
      }
      float wLk = wl[k>>1][k&1], wRk = wr[k>>1][k&1];
      qL += wLk*(sa.x + sa.y);
      qR += wRk*(ra.x + ra.y);
    }
    float v = (m <= 10) ? (coefL*qL + coefR*qR) : 0.0f;
    v += __shfl_down(v, 8, 16);
    v += __shfl_down(v, 4, 16);
    v += __shfl_down(v, 2, 16);
    v += __shfl_down(v, 1, 16);
    if (m == 0) {
      if (h == 0) v += ws[WS_CONST + o];
      atomicAdd(out + b*4 + o, v);
    }
  }
}

extern "C" void kernel_launch(void* const* d_in, const int* in_sizes, int n_in,
                              void* d_out, int out_size, void* d_ws, size_t ws_size,
                              hipStream_t stream) {
  const float* x   = (const float*)d_in[0];
  const float* W1  = (const float*)d_in[1];
  const float* W2  = (const float*)d_in[2];
  const float* rm  = (const float*)d_in[3];
  const float* bn  = (const float*)d_in[4];
  const float* cw  = (const float*)d_in[5];
  const float* cb  = (const float*)d_in[6];
  const float* fw  = (const float*)d_in[7];
  const float* fb  = (const float*)d_in[8];
  float* out = (float*)d_out;
  float* ws  = (float*)d_ws;

  prep_kernel<<<27, 256, 0, stream>>>(rm, bn, W1, W2, cw, fw, cb, fb, ws, out);
  main_kernel<<<864, 256, 0, stream>>>(x, ws, out);
}

// Round 4
// 336.613 us; speedup vs baseline: 2.0750x; 2.0750x over previous
//
#include <hip/hip_runtime.h>

// ---------------------------------------------------------------------------
// Tensor_CSPNet forward, restructured:
//   out[b,o] = sum_h <G[o,h], log(V_h^T X[b,h] V_h + D_h)> + const[o]
// ReEig stages are provably no-ops (all eigenvalues >= 0.5 >> 1e-4).
// Eigensolve: one-sided Hestenes Jacobi, pair-per-lane in registers,
// 16-lane groups (11 active), DPP circle-method migration.
// R16: prep Jacobi(bn,rm) -> block-parallel coupled Newton-Schulz (-13us).
// R17: prep G-pass coalesced (-9us). Prep now ~20us by model.
// R18: FAILED. 4-wave blocks with __launch_bounds__(256,8) = 8 waves/EU
// -> 64-VGPR budget squeezed to 32 -> full spill of the 88-float
// register state: FETCH 16.5MB->690MB, WRITE 0.9MB->617MB (1.3GB
// scratch @ 2.1TB/s = 657us). The TLP hypothesis was never tested.
// R19: same 4-wave blocks, __launch_bounds__(256,4) -> 128-VGPR budget,
// kernel fits at ~64 VGPR -> no spills, HW can run up to 8 waves/SIMD.
// ---------------------------------------------------------------------------

#define WS_CONST 484                     // 4     : fc_w@conv_b + fc_b
#define WS_VT    512                     // 27*484: Vt[h][j][k] = V_h[k][j]
#define WS_V     (512 + 13068)           // 27*528: V[h][k][j], rows padded to 24
#define WS_D     (13580 + 14256)         // 27*484: D_h row-major (sym)
#define WS_G     (27836 + 13068)         // 4*27*528: G[o][h], rows padded to 24
#define G_STRIDE 528
#define V_STRIDE 528

typedef float v2f __attribute__((ext_vector_type(2)));

static __device__ __forceinline__ float dpp_shl1(float x) { // lane m <- lane m+1 (within 16-row)
  return __int_as_float(__builtin_amdgcn_mov_dpp(__float_as_int(x), 0x101, 0xf, 0xf, true));
}
static __device__ __forceinline__ float dpp_shr1(float x) { // lane m <- lane m-1 (within 16-row)
  return __int_as_float(__builtin_amdgcn_mov_dpp(__float_as_int(x), 0x111, 0xf, 0xf, true));
}

// one-sided Jacobi sweeps on column pairs held in registers (16-lane groups,
// lanes 0..10 active). Per-matrix convergence: offF2 = sum over the sweep's
// 231 pair-tests of d^2; exit at sweep s>=minsweep if previous sweep had
// offF2 <= eps2 * sum(lambda_i^2) for ALL 4 matrices in the wave.
static __device__ __forceinline__ void jacobi_sweeps(v2f wl[11], v2f wr[11],
                                                     bool is0, bool is10, bool inert,
                                                     int minsweep, float eps2) {
  int okprev = 0;
  #pragma unroll 1
  for (int sweep = 0; sweep < 5; ++sweep) {
    if (sweep >= minsweep && __all(okprev)) break;
    // fresh norms each sweep
    v2f na = (v2f)(0.f), nb = (v2f)(0.f);
    #pragma unroll
    for (int i = 0; i < 11; ++i) { na += wl[i]*wl[i]; nb += wr[i]*wr[i]; }
    float nL = na.x + na.y, nR = nb.x + nb.y;
    // Q = sum lambda_i^4 over the group's 22 columns (inert lanes gated out)
    float q = inert ? 0.f : (nL*nL + nR*nR);
    q += __shfl_xor(q, 1, 16);
    q += __shfl_xor(q, 2, 16);
    q += __shfl_xor(q, 4, 16);
    q += __shfl_xor(q, 8, 16);
    float dacc = 0.f;
    #pragma unroll 1
    for (int r = 0; r < 21; ++r) {
      v2f da = (v2f)(0.f), db = (v2f)(0.f);
      #pragma unroll
      for (int i = 0; i < 10; i += 2) { da += wl[i]*wr[i]; db += wl[i+1]*wr[i+1]; }
      da += wl[10]*wr[10];
      float d = (da.x + da.y) + (db.x + db.y);
      dacc += d*d;
      // R9 rotation math (measured fastest): tau chain
      float ad  = fabsf(d);
      float tau = (nR - nL)*0.5f*__builtin_amdgcn_rcpf(d);
      float sq  = sqrtf(1.0f + tau*tau);
      float t   = copysignf(__builtin_amdgcn_rcpf(fabsf(tau) + sq), tau);
      float c   = __builtin_amdgcn_rsqf(1.0f + t*t);
      float s   = t*c;
      bool tiny = (ad < 1e-28f);
      c = tiny ? 1.0f : c;
      s = tiny ? 0.0f : s;
      float cc = c*c, ss = s*s, cs2 = 2.0f*c*s;
      float nLn = cc*nL - cs2*d + ss*nR;
      float nRn = ss*nL + cs2*d + cc*nR;
      v2f cv = (v2f)(c), sv = (v2f)(s);
      #pragma unroll
      for (int i = 0; i < 11; ++i) {
        v2f nl = cv*wl[i] - sv*wr[i];
        v2f nr = sv*wl[i] + cv*wr[i];
        float tlx = dpp_shl1(nl.x), tly = dpp_shl1(nl.y);
        float trx = dpp_shr1(nr.x), trY = dpp_shr1(nr.y);
        wl[i].x = is0 ? nl.x : (is10 ? nr.x : tlx);
        wl[i].y = is0 ? nl.y : (is10 ? nr.y : tly);
        wr[i].x = is0 ? tlx : trx;
        wr[i].y = is0 ? tly : trY;
      }
      {
        float tl = dpp_shl1(nLn), tr = dpp_shr1(nRn);
        nL = is0 ? nLn : (is10 ? nRn : tl);
        nR = is0 ? tl : tr;
      }
    }
    float ds = inert ? 0.f : dacc;     // gate junk/NaN AFTER accumulation
    ds += __shfl_xor(ds, 1, 16);
    ds += __shfl_xor(ds, 2, 16);
    ds += __shfl_xor(ds, 4, 16);
    ds += __shfl_xor(ds, 8, 16);
    okprev = (ds <= eps2*q);
  }
}

// ---------------- prep: NS(bn,rm) -> S -> per-h Vt, V, D, G ----------------
// Coupled Newton-Schulz (all 256 threads, LDS matmuls):
//   A' = A/||A||_F ; Y0=A', Z0=I
//   T = 3I - Z@Y ; Y <- 0.5*Y@T ; Z <- 0.5*T@Z     (K=11 iterations)
//   Y -> A'^{1/2}, Z -> A'^{-1/2}
// S = rm^{-1/2} @ bn^{1/2} = sqrt(c_bn/c_rm) * Z_rm @ Y_bn.
__global__ void prep_kernel(const float* __restrict__ rm, const float* __restrict__ bn,
                            const float* __restrict__ W1, const float* __restrict__ W2,
                            const float* __restrict__ conv_w, const float* __restrict__ fc_w,
                            const float* __restrict__ conv_b, const float* __restrict__ fc_b,
                            float* __restrict__ ws, float* __restrict__ out) {
  __shared__ float sW1[1024] __attribute__((aligned(16)));
  __shared__ float sW2[704]  __attribute__((aligned(16)));
  __shared__ float sY[2][2][484] __attribute__((aligned(16)));  // [mat][buf][..]
  __shared__ float sZ[2][2][484] __attribute__((aligned(16)));
  __shared__ float sT[2][484]    __attribute__((aligned(16)));
  __shared__ float sS[484]  __attribute__((aligned(16)));
  __shared__ float sU[704]  __attribute__((aligned(16)));
  __shared__ float sE[220]  __attribute__((aligned(16)));
  __shared__ float sG[1936] __attribute__((aligned(16)));
  __shared__ float sC[2];
  const int tid = threadIdx.x, h = blockIdx.x;

  if (h == 0)  // zero the atomic-add target (replaces memset dispatch)
    for (int idx = tid; idx < 2048; idx += 256) out[idx] = 0.f;

  // phase A: waves 0/1 compute Frobenius norms of bn/rm; waves 2/3 stage W1,W2
  const int wv = tid >> 6, ln = tid & 63;
  if (wv < 2) {
    const float* src = wv ? rm : bn;
    float s = 0.f;
    for (int i = ln; i < 484; i += 64) { float v = src[i]; s += v*v; }
    s += __shfl_xor(s, 1);  s += __shfl_xor(s, 2);  s += __shfl_xor(s, 4);
    s += __shfl_xor(s, 8);  s += __shfl_xor(s, 16); s += __shfl_xor(s, 32);
    if (ln == 0) sC[wv] = sqrtf(s);
  } else {
    const int t = tid - 128;
    for (int i = t; i < 1024; i += 128) sW1[i] = W1[h*1024 + i];
    for (int i = t; i < 704;  i += 128) sW2[i] = W2[h*704 + i];
  }
  __syncthreads();

  // phase B: init Y = A/c, Z = I for both matrices
  {
    const float ic0 = 1.0f/sC[0], ic1 = 1.0f/sC[1];
    for (int idx = tid; idx < 484; idx += 256) {
      const int i = idx/22, j = idx - 22*i;
      const float e = (i == j) ? 1.f : 0.f;
      sY[0][0][idx] = bn[idx]*ic0;  sZ[0][0][idx] = e;
      sY[1][0][idx] = rm[idx]*ic1;  sZ[1][0][idx] = e;
    }
  }
  __syncthreads();

  // phase C: K=11 coupled NS iterations (v2f column pairs: 22 rows x 11 pairs)
  int cur = 0;
  #pragma unroll 1
  for (int it = 0; it < 11; ++it) {
    // T = 3I - Z@Y (both matrices: 484 v2f elements)
    for (int idx = tid; idx < 484; idx += 256) {
      const int mt = (idx >= 242), r = idx - mt*242, i = r/11, jp = r - 11*i;
      const float* Zc = sZ[mt][cur];
      const float* Yc = sY[mt][cur];
      v2f acc = (v2f)(0.f);
      #pragma unroll
      for (int k = 0; k < 22; ++k)
        acc += *(const v2f*)(Yc + k*22 + 2*jp) * Zc[i*22 + k];
      v2f tv;
      tv.x = ((2*jp     == i) ? 3.f : 0.f) - acc.x;
      tv.y = ((2*jp + 1 == i) ? 3.f : 0.f) - acc.y;
      *(v2f*)(sT[mt] + i*22 + 2*jp) = tv;
    }
    __syncthreads();
    // Ynew = 0.5*Y@T ; Znew = 0.5*T@Z  (968 v2f elements)
    for (int idx = tid; idx < 968; idx += 256) {
      const int sel = idx/242, r = idx - 242*sel, i = r/11, jp = r - 11*i;
      const int mt = sel >> 1; const bool isZ = sel & 1;
      const float* A = isZ ? sT[mt] : sY[mt][cur];
      const float* B = isZ ? sZ[mt][cur] : sT[mt];
      v2f acc = (v2f)(0.f);
      #pragma unroll
      for (int k = 0; k < 22; ++k)
        acc += *(const v2f*)(B + k*22 + 2*jp) * A[i*22 + k];
      *(v2f*)((isZ ? sZ[mt][cur^1] : sY[mt][cur^1]) + i*22 + 2*jp) = 0.5f*acc;
    }
    __syncthreads();
    cur ^= 1;   // data now lives in buffer 'cur'
  }

  // phase D: S = sqrt(c_bn/c_rm)*Z_rm@Y_bn ; U = W1@W2 ; raw G (coalesced)
  {
    const float scale = sqrtf(sC[0]/sC[1]);
    const float* Zrm = sZ[1][cur];
    const float* Ybn = sY[0][cur];
    for (int idx = tid; idx < 484; idx += 256) {
      const int i = idx/22, j = idx - 22*i;
      float s = 0.f;
      for (int k = 0; k < 22; ++k) s += Zrm[i*22+k]*Ybn[k*22+j];
      sS[idx] = scale*s;
    }
  }
  for (int idx = tid; idx < 704; idx += 256) {
    const int n = idx/22, j = idx - 22*n;
    float s = 0.f;
    for (int k = 0; k < 32; ++k) s += sW1[n*32+k]*sW2[k*22+j];
    sU[idx] = s;
  }
  // raw G, coalesced: thread t owns v2f element r = 2t,2t+1 of all 4 outputs.
  // 48 in-flight strided v2f loads (lanes contiguous per c), 4x register
  // reuse across o; fc_w indices are wave-uniform literals -> s_loads.
  if (tid < 242) {
    const int wi = h/9, bi = h - 9*wi;
    const float* base = conv_w + wi*4356 + bi*484 + 2*tid;
    v2f a0 = (v2f)(0.f), a1 = (v2f)(0.f), a2 = (v2f)(0.f), a3 = (v2f)(0.f);
    #pragma unroll
    for (int c = 0; c < 48; ++c) {
      const v2f wv2 = *(const v2f*)(base + c*13068);
      a0 += wv2*fc_w[c];
      a1 += wv2*fc_w[48+c];
      a2 += wv2*fc_w[96+c];
      a3 += wv2*fc_w[144+c];
    }
    *(v2f*)(sG +        2*tid) = a0;
    *(v2f*)(sG +  484 + 2*tid) = a1;
    *(v2f*)(sG +  968 + 2*tid) = a2;
    *(v2f*)(sG + 1452 + 2*tid) = a3;
  }
  __syncthreads();

  // V = U_top @ S: write transposed (Vt, packed) and row-major (stride 24)
  for (int idx = tid; idx < 484; idx += 256) {
    const int k = idx/22, j = idx - 22*k;
    float s = 0.f;
    for (int l = 0; l < 22; ++l) s += sU[k*22+l]*sS[l*22+j];
    ws[WS_VT + h*484 + j*22 + k] = s;
    ws[WS_V  + h*V_STRIDE + k*24 + j] = s;
  }
  // E = U_bot @ S (10x22)
  for (int idx = tid; idx < 220; idx += 256) {
    const int e = idx/22, j = idx - 22*e;
    float s = 0.f;
    for (int l = 0; l < 22; ++l) s += sU[(22+e)*22+l]*sS[l*22+j];
    sE[idx] = s;
  }
  __syncthreads();
  // D = E^T E (22x22, symmetric)
  for (int idx = tid; idx < 484; idx += 256) {
    const int i = idx/22, j = idx - 22*i;
    float s = 0.f;
    for (int e = 0; e < 10; ++e) s += sE[e*22+i]*sE[e*22+j];
    ws[WS_D + h*484 + idx] = s;
  }
  // G symmetrized into padded layout
  for (int idx = tid; idx < 1936; idx += 256) {
    const int o = idx/484, r = idx - 484*o, i = r/22, j = r - 22*i;
    const float v = 0.5f*(sG[o*484 + i*22 + j] + sG[o*484 + j*22 + i]);
    ws[WS_G + (o*27+h)*G_STRIDE + i*24 + j] = v;
  }
  if (h == 0 && tid < 4) {
    float s = 0.f;
    for (int c = 0; c < 48; ++c) s += fc_w[tid*48+c]*conv_b[c];
    ws[WS_CONST + tid] = s + fc_b[tid];
  }
}

// ---------------- main: P4 build + one-sided Jacobi + projection -----------
// 4 waves/block (256 thr); each wave = 4 matrices, identical to the old
// 1-wave blocks via gw = blockIdx*4 + wid. h wave-uniform -> V/D/G base
// pointers uniform -> scalar loads. Zero LDS. launch_bounds(256,4):
// 128-VGPR budget (kernel needs ~64; NEVER 8 -- that forced 32 VGPR and
// spilled 1.3GB to scratch, R18).
__global__ void __launch_bounds__(256, 4) main_kernel(const float* __restrict__ x,
                                                      const float* __restrict__ ws,
                                                      float* __restrict__ out) {
  const int lane = threadIdx.x & 63;
  const int wid  = threadIdx.x >> 6;
  const int gw   = blockIdx.x*4 + wid;       // global wave id, 0..3455
  const int g = lane >> 4, m = lane & 15;
  const int mm = (m < 10) ? m : 10;          // lanes 11..15 mirror pair 10 (inert)
  const int h  = gw % 27;                    // wave-uniform
  const int b  = (gw/27)*4 + g;
  const int id = b*27 + h;                   // matrix index in x

  // V column pair 2mm, 2mm+1 (rows 2mm,2mm+1 of Vt; 44 contiguous floats)
  v2f vl[11], vrr[11];
  {
    const v2f* vb = (const v2f*)(ws + WS_VT + h*484 + mm*44);
    #pragma unroll
    for (int j = 0; j < 11; ++j) { vl[j] = vb[j]; vrr[j] = vb[11+j]; }
  }
  // init w = D rows 2mm, 2mm+1 (columns of symmetric D)
  v2f wl[11], wr[11];
  {
    const v2f* d2 = (const v2f*)(ws + WS_D + h*484 + mm*44);
    #pragma unroll
    for (int j = 0; j < 11; ++j) { wl[j] = d2[j]; wr[j] = d2[11+j]; }
  }
  // streamed build: for each row k, t_k = <Xrow_k, v>, then w += V[k][:] * t_k
  {
    const v2f* X2 = (const v2f*)(x + (size_t)id * 484);
    const float* Vrow = ws + WS_V + h*V_STRIDE;
    #pragma unroll 2
    for (int k = 0; k < 22; ++k) {
      v2f aL = (v2f)(0.f), aR = (v2f)(0.f);
      #pragma unroll
      for (int c = 0; c < 11; ++c) {
        v2f xv = X2[11*k + c];
        aL += xv*vl[c];
        aR += xv*vrr[c];
      }
      float tLk = aL.x + aL.y, tRk = aR.x + aR.y;
      const v2f* vk = (const v2f*)(Vrow + k*24);
      #pragma unroll
      for (int j = 0; j < 11; ++j) {
        v2f q = vk[j];
        wl[j] += q*tLk;
        wr[j] += q*tRk;
      }
    }
  }

  jacobi_sweeps(wl, wr, (m == 0), (m == 10), (m > 10), 2, 1e-4f);

  // log-eig coefficients: L = sum_j (log lam_j / lam_j^2) w_j w_j^T, lam^2 = ||w||^2
  float nL, nR;
  {
    v2f na = (v2f)(0.f), nb = (v2f)(0.f);
    #pragma unroll
    for (int i = 0; i < 11; ++i) { na += wl[i]*wl[i]; nb += wr[i]*wr[i]; }
    nL = na.x + na.y; nR = nb.x + nb.y;
  }
  const float HALF_LN2 = 0.34657359f;        // 0.5*ln(2)
  float coefL = HALF_LN2*log2f(fmaxf(nL, 1e-8f))*__builtin_amdgcn_rcpf(nL);
  float coefR = HALF_LN2*log2f(fmaxf(nR, 1e-8f))*__builtin_amdgcn_rcpf(nR);

  // projection: out[b,o] += sum_cols coef * (w^T G[o,h] w)
  #pragma unroll 1
  for (int o = 0; o < 4; ++o) {
    const float* Gptr = ws + WS_G + (o*27+h)*G_STRIDE;
    float qL = 0.f, qR = 0.f;
    #pragma unroll
    for (int k = 0; k < 22; ++k) {
      const v2f* g2 = (const v2f*)(Gptr + k*24);
      v2f sa = (v2f)(0.f), ra = (v2f)(0.f);
      #pragma unroll
      for (int j = 0; j < 11; ++j) {
        v2f q = g2[j];
        sa += q*wl[j];
        ra += q*wr[j];
      }
      float wLk = wl[k>>1][k&1], wRk = wr[k>>1][k&1];
      qL += wLk*(sa.x + sa.y);
      qR += wRk*(ra.x + ra.y);
    }
    float v = (m <= 10) ? (coefL*qL + coefR*qR) : 0.0f;
    v += __shfl_down(v, 8, 16);
    v += __shfl_down(v, 4, 16);
    v += __shfl_down(v, 2, 16);
    v += __shfl_down(v, 1, 16);
    if (m == 0) {
      if (h == 0) v += ws[WS_CONST + o];
      atomicAdd(out + b*4 + o, v);
    }
  }
}

extern "C" void kernel_launch(void* const* d_in, const int* in_sizes, int n_in,
                              void* d_out, int out_size, void* d_ws, size_t ws_size,
                              hipStream_t stream) {
  const float* x   = (const float*)d_in[0];
  const float* W1  = (const float*)d_in[1];
  const float* W2  = (const float*)d_in[2];
  const float* rm  = (const float*)d_in[3];
  const float* bn  = (const float*)d_in[4];
  const float* cw  = (const float*)d_in[5];
  const float* cb  = (const float*)d_in[6];
  const float* fw  = (const float*)d_in[7];
  const float* fb  = (const float*)d_in[8];
  float* out = (float*)d_out;
  float* ws  = (float*)d_ws;

  prep_kernel<<<27, 256, 0, stream>>>(rm, bn, W1, W2, cw, fw, cb, fb, ws, out);
  main_kernel<<<864, 256, 0, stream>>>(x, ws, out);
}

// Round 5
// 274.803 us; speedup vs baseline: 2.5418x; 1.2249x over previous
//
#include <hip/hip_runtime.h>

// ---------------------------------------------------------------------------
// Tensor_CSPNet forward, restructured:
//   out[b,o] = sum_h <G[o,h], log(V_h^T X[b,h] V_h + D_h)> + const[o]
// ReEig stages are provably no-ops (all eigenvalues >= 0.5 >> 1e-4).
// R16: prep Jacobi(bn,rm) -> block-parallel coupled Newton-Schulz (-13us).
// R17: prep G-pass coalesced (-9us).
// R18: FAILED. launch_bounds(256,8) -> 32-VGPR squeeze -> 1.3GB scratch spill.
// R19: FAILED. 4-wave blocks, no spill, but 257us vs 229us: occupancy is
//   GRID-limited (3456 waves = 3.4/SIMD) -- block shape can't raise it;
//   4-wave blocks only added block-tail imbalance. Reverted to 64-thr.
// R20: Jacobi ordering rewrite. Old round-robin migration = 44 DPP +
//   88 cndmask per rotation (half the Jacobi VALU). New odd-even
//   transposition (Brent-Luk): step A rotates intra-lane pair (no
//   migration, swap by rename); step B borrows u=shl(wl), rotates
//   (wr,u), returns via shr; 4 cndmask/elem boundary handling. All 231
//   pairs per 22 steps (n=4 case verified by hand). ~31% Jacobi VALU cut.
// ---------------------------------------------------------------------------

#define WS_CONST 484                     // 4     : fc_w@conv_b + fc_b
#define WS_VT    512                     // 27*484: Vt[h][j][k] = V_h[k][j]
#define WS_V     (512 + 13068)           // 27*528: V[h][k][j], rows padded to 24
#define WS_D     (13580 + 14256)         // 27*484: D_h row-major (sym)
#define WS_G     (27836 + 13068)         // 4*27*528: G[o][h], rows padded to 24
#define G_STRIDE 528
#define V_STRIDE 528

typedef float v2f __attribute__((ext_vector_type(2)));

static __device__ __forceinline__ float dpp_shl1(float x) { // lane m <- lane m+1 (within 16-row)
  return __int_as_float(__builtin_amdgcn_mov_dpp(__float_as_int(x), 0x101, 0xf, 0xf, true));
}
static __device__ __forceinline__ float dpp_shr1(float x) { // lane m <- lane m-1 (within 16-row)
  return __int_as_float(__builtin_amdgcn_mov_dpp(__float_as_int(x), 0x111, 0xf, 0xf, true));
}

// One-sided Jacobi, odd-even transposition ordering (Brent-Luk).
// Lane m (m=0..10) holds columns c_{2m} (wl) and c_{2m+1} (wr); lanes 11..15
// mirror pair 10 and are inert (gated from sums; junk contained: only lane10
// reads lane11, in step B, where its rotation is forced to identity).
// Sweep = 11 double-steps (22 rounds) covering all 231 pairs.
// Convergence: offF2 (sum of d^2 over the sweep) <= eps2 * sum(lambda^2).
static __device__ __forceinline__ void jacobi_sweeps(v2f wl[11], v2f wr[11],
                                                     bool is0, bool act, bool inert,
                                                     int minsweep, float eps2) {
  int okprev = 0;
  #pragma unroll 1
  for (int sweep = 0; sweep < 5; ++sweep) {
    if (sweep >= minsweep && __all(okprev)) break;
    // fresh norms each sweep
    v2f na = (v2f)(0.f), nb = (v2f)(0.f);
    #pragma unroll
    for (int i = 0; i < 11; ++i) { na += wl[i]*wl[i]; nb += wr[i]*wr[i]; }
    float nL = na.x + na.y, nR = nb.x + nb.y;
    // Q = sum lambda_i^4 over the group's 22 columns (inert lanes gated out)
    float q = inert ? 0.f : (nL*nL + nR*nR);
    q += __shfl_xor(q, 1, 16);
    q += __shfl_xor(q, 2, 16);
    q += __shfl_xor(q, 4, 16);
    q += __shfl_xor(q, 8, 16);
    float dacc = 0.f;
    #pragma unroll 1
    for (int r = 0; r < 11; ++r) {
      // ---------- step A: rotate intra-lane pair (wl, wr); swap by rename ----
      {
        v2f da = (v2f)(0.f), db = (v2f)(0.f);
        #pragma unroll
        for (int i = 0; i < 10; i += 2) { da += wl[i]*wr[i]; db += wl[i+1]*wr[i+1]; }
        da += wl[10]*wr[10];
        float d = (da.x + da.y) + (db.x + db.y);
        dacc += d*d;
        float ad  = fabsf(d);
        float tau = (nR - nL)*0.5f*__builtin_amdgcn_rcpf(d);
        float sq  = sqrtf(1.0f + tau*tau);
        float t   = copysignf(__builtin_amdgcn_rcpf(fabsf(tau) + sq), tau);
        float c   = __builtin_amdgcn_rsqf(1.0f + t*t);
        float s   = t*c;
        bool tiny = (ad < 1e-28f);
        c = tiny ? 1.0f : c;
        s = tiny ? 0.0f : s;
        float cc = c*c, ss = s*s, cs2 = 2.0f*c*s;
        float nLn = cc*nL - cs2*d + ss*nR;   // norm of rotated-left
        float nRn = ss*nL + cs2*d + cc*nR;   // norm of rotated-right
        v2f cv = (v2f)(c), sv = (v2f)(s);
        #pragma unroll
        for (int i = 0; i < 11; ++i) {
          v2f nl = cv*wl[i] - sv*wr[i];
          v2f nr = sv*wl[i] + cv*wr[i];
          wl[i] = nr;                        // swap: pos 2m <- rotated-right
          wr[i] = nl;                        //       pos 2m+1 <- rotated-left
        }
        nL = nRn; nR = nLn;
      }
      // ---------- step B: u = shl(wl) = c_{2m+2}; rotate (wr, u), lanes m<10 --
      {
        v2f u[11];
        #pragma unroll
        for (int i = 0; i < 11; ++i) { u[i].x = dpp_shl1(wl[i].x); u[i].y = dpp_shl1(wl[i].y); }
        float nU = dpp_shl1(nL);
        v2f da = (v2f)(0.f), db = (v2f)(0.f);
        #pragma unroll
        for (int i = 0; i < 10; i += 2) { da += wr[i]*u[i]; db += wr[i+1]*u[i+1]; }
        da += wr[10]*u[10];
        float d = (da.x + da.y) + (db.x + db.y);
        d = act ? d : 0.f;                   // lane>=10: identity rotation (c=1,s=0)
        dacc += d*d;
        float ad  = fabsf(d);
        float tau = (nU - nR)*0.5f*__builtin_amdgcn_rcpf(d);
        float sq  = sqrtf(1.0f + tau*tau);
        float t   = copysignf(__builtin_amdgcn_rcpf(fabsf(tau) + sq), tau);
        float c   = __builtin_amdgcn_rsqf(1.0f + t*t);
        float s   = t*c;
        bool tiny = (ad < 1e-28f);
        c = tiny ? 1.0f : c;
        s = tiny ? 0.0f : s;
        float cc = c*c, ss = s*s, cs2 = 2.0f*c*s;
        v2f cv = (v2f)(c), sv = (v2f)(s);
        #pragma unroll
        for (int i = 0; i < 11; ++i) {
          v2f rl = cv*wr[i] - sv*u[i];       // rotated-left  -> pos 2m+2 (lane m+1's wl)
          v2f rr = sv*wr[i] + cv*u[i];       // rotated-right -> pos 2m+1 (stays, if active)
          wr[i].x = act ? rr.x : wr[i].x;
          wr[i].y = act ? rr.y : wr[i].y;
          float bx = dpp_shr1(rl.x), by = dpp_shr1(rl.y);
          wl[i].x = is0 ? wl[i].x : bx;
          wl[i].y = is0 ? wl[i].y : by;
        }
        float nRn = ss*nR + cs2*d + cc*nU;   // norm of rotated-right
        float nLg = cc*nR - cs2*d + ss*nU;   // norm of rotated-left (gated lane: = nR)
        nR = act ? nRn : nR;
        float bn2 = dpp_shr1(nLg);
        nL = is0 ? nL : bn2;
      }
    }
    float ds = inert ? 0.f : dacc;     // gate junk/NaN AFTER accumulation
    ds += __shfl_xor(ds, 1, 16);
    ds += __shfl_xor(ds, 2, 16);
    ds += __shfl_xor(ds, 4, 16);
    ds += __shfl_xor(ds, 8, 16);
    okprev = (ds <= eps2*q);
  }
}

// ---------------- prep: NS(bn,rm) -> S -> per-h Vt, V, D, G ----------------
// Coupled Newton-Schulz (all 256 threads, LDS matmuls):
//   A' = A/||A||_F ; Y0=A', Z0=I
//   T = 3I - Z@Y ; Y <- 0.5*Y@T ; Z <- 0.5*T@Z     (K=11 iterations)
//   Y -> A'^{1/2}, Z -> A'^{-1/2}
// S = rm^{-1/2} @ bn^{1/2} = sqrt(c_bn/c_rm) * Z_rm @ Y_bn.
__global__ void prep_kernel(const float* __restrict__ rm, const float* __restrict__ bn,
                            const float* __restrict__ W1, const float* __restrict__ W2,
                            const float* __restrict__ conv_w, const float* __restrict__ fc_w,
                            const float* __restrict__ conv_b, const float* __restrict__ fc_b,
                            float* __restrict__ ws, float* __restrict__ out) {
  __shared__ float sW1[1024] __attribute__((aligned(16)));
  __shared__ float sW2[704]  __attribute__((aligned(16)));
  __shared__ float sY[2][2][484] __attribute__((aligned(16)));  // [mat][buf][..]
  __shared__ float sZ[2][2][484] __attribute__((aligned(16)));
  __shared__ float sT[2][484]    __attribute__((aligned(16)));
  __shared__ float sS[484]  __attribute__((aligned(16)));
  __shared__ float sU[704]  __attribute__((aligned(16)));
  __shared__ float sE[220]  __attribute__((aligned(16)));
  __shared__ float sG[1936] __attribute__((aligned(16)));
  __shared__ float sC[2];
  const int tid = threadIdx.x, h = blockIdx.x;

  if (h == 0)  // zero the atomic-add target (replaces memset dispatch)
    for (int idx = tid; idx < 2048; idx += 256) out[idx] = 0.f;

  // phase A: waves 0/1 compute Frobenius norms of bn/rm; waves 2/3 stage W1,W2
  const int wv = tid >> 6, ln = tid & 63;
  if (wv < 2) {
    const float* src = wv ? rm : bn;
    float s = 0.f;
    for (int i = ln; i < 484; i += 64) { float v = src[i]; s += v*v; }
    s += __shfl_xor(s, 1);  s += __shfl_xor(s, 2);  s += __shfl_xor(s, 4);
    s += __shfl_xor(s, 8);  s += __shfl_xor(s, 16); s += __shfl_xor(s, 32);
    if (ln == 0) sC[wv] = sqrtf(s);
  } else {
    const int t = tid - 128;
    for (int i = t; i < 1024; i += 128) sW1[i] = W1[h*1024 + i];
    for (int i = t; i < 704;  i += 128) sW2[i] = W2[h*704 + i];
  }
  __syncthreads();

  // phase B: init Y = A/c, Z = I for both matrices
  {
    const float ic0 = 1.0f/sC[0], ic1 = 1.0f/sC[1];
    for (int idx = tid; idx < 484; idx += 256) {
      const int i = idx/22, j = idx - 22*i;
      const float e = (i == j) ? 1.f : 0.f;
      sY[0][0][idx] = bn[idx]*ic0;  sZ[0][0][idx] = e;
      sY[1][0][idx] = rm[idx]*ic1;  sZ[1][0][idx] = e;
    }
  }
  __syncthreads();

  // phase C: K=11 coupled NS iterations (v2f column pairs: 22 rows x 11 pairs)
  int cur = 0;
  #pragma unroll 1
  for (int it = 0; it < 11; ++it) {
    // T = 3I - Z@Y (both matrices: 484 v2f elements)
    for (int idx = tid; idx < 484; idx += 256) {
      const int mt = (idx >= 242), r = idx - mt*242, i = r/11, jp = r - 11*i;
      const float* Zc = sZ[mt][cur];
      const float* Yc = sY[mt][cur];
      v2f acc = (v2f)(0.f);
      #pragma unroll
      for (int k = 0; k < 22; ++k)
        acc += *(const v2f*)(Yc + k*22 + 2*jp) * Zc[i*22 + k];
      v2f tv;
      tv.x = ((2*jp     == i) ? 3.f : 0.f) - acc.x;
      tv.y = ((2*jp + 1 == i) ? 3.f : 0.f) - acc.y;
      *(v2f*)(sT[mt] + i*22 + 2*jp) = tv;
    }
    __syncthreads();
    // Ynew = 0.5*Y@T ; Znew = 0.5*T@Z  (968 v2f elements)
    for (int idx = tid; idx < 968; idx += 256) {
      const int sel = idx/242, r = idx - 242*sel, i = r/11, jp = r - 11*i;
      const int mt = sel >> 1; const bool isZ = sel & 1;
      const float* A = isZ ? sT[mt] : sY[mt][cur];
      const float* B = isZ ? sZ[mt][cur] : sT[mt];
      v2f acc = (v2f)(0.f);
      #pragma unroll
      for (int k = 0; k < 22; ++k)
        acc += *(const v2f*)(B + k*22 + 2*jp) * A[i*22 + k];
      *(v2f*)((isZ ? sZ[mt][cur^1] : sY[mt][cur^1]) + i*22 + 2*jp) = 0.5f*acc;
    }
    __syncthreads();
    cur ^= 1;   // data now lives in buffer 'cur'
  }

  // phase D: S = sqrt(c_bn/c_rm)*Z_rm@Y_bn ; U = W1@W2 ; raw G (coalesced)
  {
    const float scale = sqrtf(sC[0]/sC[1]);
    const float* Zrm = sZ[1][cur];
    const float* Ybn = sY[0][cur];
    for (int idx = tid; idx < 484; idx += 256) {
      const int i = idx/22, j = idx - 22*i;
      float s = 0.f;
      for (int k = 0; k < 22; ++k) s += Zrm[i*22+k]*Ybn[k*22+j];
      sS[idx] = scale*s;
    }
  }
  for (int idx = tid; idx < 704; idx += 256) {
    const int n = idx/22, j = idx - 22*n;
    float s = 0.f;
    for (int k = 0; k < 32; ++k) s += sW1[n*32+k]*sW2[k*22+j];
    sU[idx] = s;
  }
  // raw G, coalesced: thread t owns v2f element r = 2t,2t+1 of all 4 outputs.
  if (tid < 242) {
    const int wi = h/9, bi = h - 9*wi;
    const float* base = conv_w + wi*4356 + bi*484 + 2*tid;
    v2f a0 = (v2f)(0.f), a1 = (v2f)(0.f), a2 = (v2f)(0.f), a3 = (v2f)(0.f);
    #pragma unroll
    for (int c = 0; c < 48; ++c) {
      const v2f wv2 = *(const v2f*)(base + c*13068);
      a0 += wv2*fc_w[c];
      a1 += wv2*fc_w[48+c];
      a2 += wv2*fc_w[96+c];
      a3 += wv2*fc_w[144+c];
    }
    *(v2f*)(sG +        2*tid) = a0;
    *(v2f*)(sG +  484 + 2*tid) = a1;
    *(v2f*)(sG +  968 + 2*tid) = a2;
    *(v2f*)(sG + 1452 + 2*tid) = a3;
  }
  __syncthreads();

  // V = U_top @ S: write transposed (Vt, packed) and row-major (stride 24)
  for (int idx = tid; idx < 484; idx += 256) {
    const int k = idx/22, j = idx - 22*k;
    float s = 0.f;
    for (int l = 0; l < 22; ++l) s += sU[k*22+l]*sS[l*22+j];
    ws[WS_VT + h*484 + j*22 + k] = s;
    ws[WS_V  + h*V_STRIDE + k*24 + j] = s;
  }
  // E = U_bot @ S (10x22)
  for (int idx = tid; idx < 220; idx += 256) {
    const int e = idx/22, j = idx - 22*e;
    float s = 0.f;
    for (int l = 0; l < 22; ++l) s += sU[(22+e)*22+l]*sS[l*22+j];
    sE[idx] = s;
  }
  __syncthreads();
  // D = E^T E (22x22, symmetric)
  for (int idx = tid; idx < 484; idx += 256) {
    const int i = idx/22, j = idx - 22*i;
    float s = 0.f;
    for (int e = 0; e < 10; ++e) s += sE[e*22+i]*sE[e*22+j];
    ws[WS_D + h*484 + idx] = s;
  }
  // G symmetrized into padded layout
  for (int idx = tid; idx < 1936; idx += 256) {
    const int o = idx/484, r = idx - 484*o, i = r/22, j = r - 22*i;
    const float v = 0.5f*(sG[o*484 + i*22 + j] + sG[o*484 + j*22 + i]);
    ws[WS_G + (o*27+h)*G_STRIDE + i*24 + j] = v;
  }
  if (h == 0 && tid < 4) {
    float s = 0.f;
    for (int c = 0; c < 48; ++c) s += fc_w[tid*48+c]*conv_b[c];
    ws[WS_CONST + tid] = s + fc_b[tid];
  }
}

// ---------------- main: P4 build + one-sided Jacobi + projection -----------
// h is wave-uniform -> V/D/G base pointers uniform -> scalar loads (SMEM).
// Zero LDS; 64-thread blocks (4 matrices) for even CU balance (R19: bigger
// blocks regressed; occupancy is grid-limited at 3.4 waves/SIMD).
__global__ void __launch_bounds__(64, 3) main_kernel(const float* __restrict__ x,
                                                     const float* __restrict__ ws,
                                                     float* __restrict__ out) {
  const int lane = threadIdx.x;
  const int g = lane >> 4, m = lane & 15;
  const int mm = (m < 10) ? m : 10;          // lanes 11..15 mirror pair 10 (inert)
  const int h  = blockIdx.x % 27;            // wave-uniform
  const int b  = (blockIdx.x/27)*4 + g;
  const int id = b*27 + h;                   // matrix index in x

  // V column pair 2mm, 2mm+1 (rows 2mm,2mm+1 of Vt; 44 contiguous floats)
  v2f vl[11], vrr[11];
  {
    const v2f* vb = (const v2f*)(ws + WS_VT + h*484 + mm*44);
    #pragma unroll
    for (int j = 0; j < 11; ++j) { vl[j] = vb[j]; vrr[j] = vb[11+j]; }
  }
  // init w = D rows 2mm, 2mm+1 (columns of symmetric D)
  v2f wl[11], wr[11];
  {
    const v2f* d2 = (const v2f*)(ws + WS_D + h*484 + mm*44);
    #pragma unroll
    for (int j = 0; j < 11; ++j) { wl[j] = d2[j]; wr[j] = d2[11+j]; }
  }
  // streamed build: for each row k, t_k = <Xrow_k, v>, then w += V[k][:] * t_k
  {
    const v2f* X2 = (const v2f*)(x + (size_t)id * 484);
    const float* Vrow = ws + WS_V + h*V_STRIDE;
    #pragma unroll 2
    for (int k = 0; k < 22; ++k) {
      v2f aL = (v2f)(0.f), aR = (v2f)(0.f);
      #pragma unroll
      for (int c = 0; c < 11; ++c) {
        v2f xv = X2[11*k + c];
        aL += xv*vl[c];
        aR += xv*vrr[c];
      }
      float tLk = aL.x + aL.y, tRk = aR.x + aR.y;
      const v2f* vk = (const v2f*)(Vrow + k*24);
      #pragma unroll
      for (int j = 0; j < 11; ++j) {
        v2f q = vk[j];
        wl[j] += q*tLk;
        wr[j] += q*tRk;
      }
    }
  }

  jacobi_sweeps(wl, wr, (m == 0), (m < 10), (m > 10), 2, 1e-4f);

  // log-eig coefficients: L = sum_j (log lam_j / lam_j^2) w_j w_j^T, lam^2 = ||w||^2
  float nL, nR;
  {
    v2f na = (v2f)(0.f), nb = (v2f)(0.f);
    #pragma unroll
    for (int i = 0; i < 11; ++i) { na += wl[i]*wl[i]; nb += wr[i]*wr[i]; }
    nL = na.x + na.y; nR = nb.x + nb.y;
  }
  const float HALF_LN2 = 0.34657359f;        // 0.5*ln(2)
  float coefL = HALF_LN2*log2f(fmaxf(nL, 1e-8f))*__builtin_amdgcn_rcpf(nL);
  float coefR = HALF_LN2*log2f(fmaxf(nR, 1e-8f))*__builtin_amdgcn_rcpf(nR);

  // projection: out[b,o] += sum_cols coef * (w^T G[o,h] w)
  #pragma unroll 1
  for (int o = 0; o < 4; ++o) {
    const float* Gptr = ws + WS_G + (o*27+h)*G_STRIDE;
    float qL = 0.f, qR = 0.f;
    #pragma unroll
    for (int k = 0; k < 22; ++k) {
      const v2f* g2 = (const v2f*)(Gptr + k*24);
      v2f sa = (v2f)(0.f), ra = (v2f)(0.f);
      #pragma unroll
      for (int j = 0; j < 11; ++j) {
        v2f q = g2[j];
        sa += q*wl[j];
        ra += q*wr[j];
      }
      float wLk = wl[k>>1][k&1], wRk = wr[k>>1][k&1];
      qL += wLk*(sa.x + sa.y);
      qR += wRk*(ra.x + ra.y);
    }
    float v = (m <= 10) ? (coefL*qL + coefR*qR) : 0.0f;
    v += __shfl_down(v, 8, 16);
    v += __shfl_down(v, 4, 16);
    v += __shfl_down(v, 2, 16);
    v += __shfl_down(v, 1, 16);
    if (m == 0) {
      if (h == 0) v += ws[WS_CONST + o];
      atomicAdd(out + b*4 + o, v);
    }
  }
}

extern "C" void kernel_launch(void* const* d_in, const int* in_sizes, int n_in,
                              void* d_out, int out_size, void* d_ws, size_t ws_size,
                              hipStream_t stream) {
  const float* x   = (const float*)d_in[0];
  const float* W1  = (const float*)d_in[1];
  const float* W2  = (const float*)d_in[2];
  const float* rm  = (const float*)d_in[3];
  const float* bn  = (const float*)d_in[4];
  const float* cw  = (const float*)d_in[5];
  const float* cb  = (const float*)d_in[6];
  const float* fw  = (const float*)d_in[7];
  const float* fb  = (const float*)d_in[8];
  float* out = (float*)d_out;
  float* ws  = (float*)d_ws;

  prep_kernel<<<27, 256, 0, stream>>>(rm, bn, W1, W2, cw, fw, cb, fb, ws, out);
  main_kernel<<<3456, 64, 0, stream>>>(x, ws, out);
}

// Round 6
// 268.571 us; speedup vs baseline: 2.6008x; 1.0232x over previous
//
#include <hip/hip_runtime.h>

// ---------------------------------------------------------------------------
// Tensor_CSPNet forward, restructured:
//   out[b,o] = sum_h <G[o,h], log(V_h^T X[b,h] V_h + D_h)> + const[o]
// ReEig stages are provably no-ops (all eigenvalues >= 0.5 >> 1e-4).
// R16: prep Jacobi(bn,rm) -> block-parallel coupled Newton-Schulz (-13us).
// R17: prep G-pass coalesced (-9us).
// R18: FAILED. launch_bounds(256,8) -> 32-VGPR squeeze -> 1.3GB scratch spill.
// R19: FAILED. 4-wave blocks: occupancy is GRID-limited (3456 waves =
//   3.4/SIMD); block shape can't raise it. 64-thr blocks are right.
// R20: WIN (-40us main). Odd-even transposition (Brent-Luk) ordering:
//   step A intra-lane rotate+swap, step B neighbor rotate via DPP.
// R21: rotation-math + boundary-select surgery:
//   (a) direct c,s form: invr=rsq(mu^2+d^2); cos2t=|mu|*invr;
//       c=sqrt((1+cos2t)/2); cs2=sign(mu)*d*invr (free sin2t = the 2cs
//       the norm updates need); s=0.5*cs2*rcp(c). 3 transcendentals,
//       depth ~8 (was 4 trans, depth ~11), no division by d -> only
//       guard is r2~0 (both mu,d tiny). Same inner rotation as t-form.
//   (b) step-B writeback via update_dpp(old,src,row_shr:1,bound_ctrl=0):
//       lane-0-keeps-old merges the is0 cndmask into the DPP op
//       (3 instr -> 1 per element per round).
//   NOTE: do NOT "role-swap" step B to kill the act-select: without the
//   positional swap the transposition network stops migrating columns
//   and the sweep no longer meets all 231 pairs.
// ---------------------------------------------------------------------------

#define WS_CONST 484                     // 4     : fc_w@conv_b + fc_b
#define WS_VT    512                     // 27*484: Vt[h][j][k] = V_h[k][j]
#define WS_V     (512 + 13068)           // 27*528: V[h][k][j], rows padded to 24
#define WS_D     (13580 + 14256)         // 27*484: D_h row-major (sym)
#define WS_G     (27836 + 13068)         // 4*27*528: G[o][h], rows padded to 24
#define G_STRIDE 528
#define V_STRIDE 528

typedef float v2f __attribute__((ext_vector_type(2)));

static __device__ __forceinline__ float dpp_shl1(float x) { // lane m <- lane m+1 (within 16-row)
  return __int_as_float(__builtin_amdgcn_mov_dpp(__float_as_int(x), 0x101, 0xf, 0xf, true));
}
// lane m <- lane m-1 within 16-row; lane 0 of each row KEEPS old (bound_ctrl=false)
static __device__ __forceinline__ float upd_shr1(float old, float x) {
  return __int_as_float(__builtin_amdgcn_update_dpp(
      __float_as_int(old), __float_as_int(x), 0x111, 0xf, 0xf, false));
}

// Direct Jacobi rotation from Gram entries (nL, d, nR):
//   mu = (nR-nL)/2; r = sqrt(mu^2+d^2); cos2t = |mu|/r (inner rotation)
//   c = sqrt((1+cos2t)/2); cs2 = 2cs = sign(mu)*d/r; s = cs2/(2c)
// Identical rotation to the t-chain form; no division by d.
static __device__ __forceinline__ void rot_cs(float nL, float nR, float d,
                                              float& c, float& s,
                                              float& c2, float& ss, float& cs2) {
  float mu   = 0.5f*(nR - nL);
  float r2   = __builtin_fmaf(mu, mu, d*d);
  float invr = __builtin_amdgcn_rsqf(r2);
  bool  degen = (r2 < 1e-40f);
  float co = fminf(fabsf(mu)*invr, 1.0f);
  co = degen ? 1.0f : co;
  c2 = __builtin_fmaf(0.5f, co, 0.5f);
  c  = sqrtf(c2);
  float cinv = __builtin_amdgcn_rcpf(c);
  float t2 = d*invr;
  t2 = (mu < 0.0f) ? -t2 : t2;
  cs2 = degen ? 0.0f : t2;
  s  = 0.5f*cs2*cinv;
  ss = 1.0f - c2;
}

// One-sided Jacobi, odd-even transposition ordering (Brent-Luk).
// Lane m (m=0..10) holds columns c_{2m} (wl) and c_{2m+1} (wr); lanes 11..15
// mirror pair 10 and are inert (gated from sums; junk contained: only lane10
// reads lane11, in step B, where its rotation is forced to identity).
// Sweep = 11 double-steps (22 rounds) covering all 231 pairs.
// Convergence: offF2 (sum of d^2 over the sweep) <= eps2 * sum(lambda^2).
static __device__ __forceinline__ void jacobi_sweeps(v2f wl[11], v2f wr[11],
                                                     bool act, bool inert,
                                                     int minsweep, float eps2) {
  int okprev = 0;
  #pragma unroll 1
  for (int sweep = 0; sweep < 5; ++sweep) {
    if (sweep >= minsweep && __all(okprev)) break;
    // fresh norms each sweep
    v2f na = (v2f)(0.f), nb = (v2f)(0.f);
    #pragma unroll
    for (int i = 0; i < 11; ++i) { na += wl[i]*wl[i]; nb += wr[i]*wr[i]; }
    float nL = na.x + na.y, nR = nb.x + nb.y;
    // Q = sum lambda_i^4 over the group's 22 columns (inert lanes gated out)
    float q = inert ? 0.f : (nL*nL + nR*nR);
    q += __shfl_xor(q, 1, 16);
    q += __shfl_xor(q, 2, 16);
    q += __shfl_xor(q, 4, 16);
    q += __shfl_xor(q, 8, 16);
    float dacc = 0.f;
    #pragma unroll 1
    for (int r = 0; r < 11; ++r) {
      // ---------- step A: rotate intra-lane pair (wl, wr); swap by rename ----
      {
        v2f da = (v2f)(0.f), db = (v2f)(0.f);
        #pragma unroll
        for (int i = 0; i < 10; i += 2) { da += wl[i]*wr[i]; db += wl[i+1]*wr[i+1]; }
        da += wl[10]*wr[10];
        float d = (da.x + da.y) + (db.x + db.y);
        dacc += d*d;
        float c, s, c2, ss, cs2;
        rot_cs(nL, nR, d, c, s, c2, ss, cs2);
        float nLn = c2*nL - cs2*d + ss*nR;   // norm of rotated-left
        float nRn = ss*nL + cs2*d + c2*nR;   // norm of rotated-right
        v2f cv = (v2f)(c), sv = (v2f)(s);
        #pragma unroll
        for (int i = 0; i < 11; ++i) {
          v2f nl = cv*wl[i] - sv*wr[i];
          v2f nr = sv*wl[i] + cv*wr[i];
          wl[i] = nr;                        // swap: pos 2m <- rotated-right
          wr[i] = nl;                        //       pos 2m+1 <- rotated-left
        }
        nL = nRn; nR = nLn;
      }
      // ---------- step B: u = shl(wl) = c_{2m+2}; rotate (wr, u), lanes m<10 --
      {
        v2f u[11];
        #pragma unroll
        for (int i = 0; i < 11; ++i) { u[i].x = dpp_shl1(wl[i].x); u[i].y = dpp_shl1(wl[i].y); }
        float nU = dpp_shl1(nL);
        v2f da = (v2f)(0.f), db = (v2f)(0.f);
        #pragma unroll
        for (int i = 0; i < 10; i += 2) { da += wr[i]*u[i]; db += wr[i+1]*u[i+1]; }
        da += wr[10]*u[10];
        float d = (da.x + da.y) + (db.x + db.y);
        d = act ? d : 0.f;                   // lane>=10: identity rotation (c=1,s=0)
        dacc += d*d;
        float c, s, c2, ss, cs2;
        rot_cs(nR, nU, d, c, s, c2, ss, cs2);
        v2f cv = (v2f)(c), sv = (v2f)(s);
        #pragma unroll
        for (int i = 0; i < 11; ++i) {
          v2f rl = cv*wr[i] - sv*u[i];       // rotated-left  -> pos 2m+2 (lane m+1's wl)
          v2f rr = sv*wr[i] + cv*u[i];       // rotated-right -> pos 2m+1 (stays, if active)
          wr[i].x = act ? rr.x : wr[i].x;
          wr[i].y = act ? rr.y : wr[i].y;
          wl[i].x = upd_shr1(wl[i].x, rl.x); // lane0 keeps old via bound_ctrl
          wl[i].y = upd_shr1(wl[i].y, rl.y);
        }
        float nRn = ss*nR + cs2*d + c2*nU;   // norm of rotated-right
        float nLg = c2*nR - cs2*d + ss*nU;   // norm of rotated-left (gated lane: = nR)
        nR = act ? nRn : nR;
        nL = upd_shr1(nL, nLg);
      }
    }
    float ds = inert ? 0.f : dacc;     // gate junk/NaN AFTER accumulation
    ds += __shfl_xor(ds, 1, 16);
    ds += __shfl_xor(ds, 2, 16);
    ds += __shfl_xor(ds, 4, 16);
    ds += __shfl_xor(ds, 8, 16);
    okprev = (ds <= eps2*q);
  }
}

// ---------------- prep: NS(bn,rm) -> S -> per-h Vt, V, D, G ----------------
// Coupled Newton-Schulz (all 256 threads, LDS matmuls):
//   A' = A/||A||_F ; Y0=A', Z0=I
//   T = 3I - Z@Y ; Y <- 0.5*Y@T ; Z <- 0.5*T@Z     (K=11 iterations)
//   Y -> A'^{1/2}, Z -> A'^{-1/2}
// S = rm^{-1/2} @ bn^{1/2} = sqrt(c_bn/c_rm) * Z_rm @ Y_bn.
__global__ void prep_kernel(const float* __restrict__ rm, const float* __restrict__ bn,
                            const float* __restrict__ W1, const float* __restrict__ W2,
                            const float* __restrict__ conv_w, const float* __restrict__ fc_w,
                            const float* __restrict__ conv_b, const float* __restrict__ fc_b,
                            float* __restrict__ ws, float* __restrict__ out) {
  __shared__ float sW1[1024] __attribute__((aligned(16)));
  __shared__ float sW2[704]  __attribute__((aligned(16)));
  __shared__ float sY[2][2][484] __attribute__((aligned(16)));  // [mat][buf][..]
  __shared__ float sZ[2][2][484] __attribute__((aligned(16)));
  __shared__ float sT[2][484]    __attribute__((aligned(16)));
  __shared__ float sS[484]  __attribute__((aligned(16)));
  __shared__ float sU[704]  __attribute__((aligned(16)));
  __shared__ float sE[220]  __attribute__((aligned(16)));
  __shared__ float sG[1936] __attribute__((aligned(16)));
  __shared__ float sC[2];
  const int tid = threadIdx.x, h = blockIdx.x;

  if (h == 0)  // zero the atomic-add target (replaces memset dispatch)
    for (int idx = tid; idx < 2048; idx += 256) out[idx] = 0.f;

  // phase A: waves 0/1 compute Frobenius norms of bn/rm; waves 2/3 stage W1,W2
  const int wv = tid >> 6, ln = tid & 63;
  if (wv < 2) {
    const float* src = wv ? rm : bn;
    float s = 0.f;
    for (int i = ln; i < 484; i += 64) { float v = src[i]; s += v*v; }
    s += __shfl_xor(s, 1);  s += __shfl_xor(s, 2);  s += __shfl_xor(s, 4);
    s += __shfl_xor(s, 8);  s += __shfl_xor(s, 16); s += __shfl_xor(s, 32);
    if (ln == 0) sC[wv] = sqrtf(s);
  } else {
    const int t = tid - 128;
    for (int i = t; i < 1024; i += 128) sW1[i] = W1[h*1024 + i];
    for (int i = t; i < 704;  i += 128) sW2[i] = W2[h*704 + i];
  }
  __syncthreads();

  // phase B: init Y = A/c, Z = I for both matrices
  {
    const float ic0 = 1.0f/sC[0], ic1 = 1.0f/sC[1];
    for (int idx = tid; idx < 484; idx += 256) {
      const int i = idx/22, j = idx - 22*i;
      const float e = (i == j) ? 1.f : 0.f;
      sY[0][0][idx] = bn[idx]*ic0;  sZ[0][0][idx] = e;
      sY[1][0][idx] = rm[idx]*ic1;  sZ[1][0][idx] = e;
    }
  }
  __syncthreads();

  // phase C: K=11 coupled NS iterations (v2f column pairs: 22 rows x 11 pairs)
  int cur = 0;
  #pragma unroll 1
  for (int it = 0; it < 11; ++it) {
    // T = 3I - Z@Y (both matrices: 484 v2f elements)
    for (int idx = tid; idx < 484; idx += 256) {
      const int mt = (idx >= 242), r = idx - mt*242, i = r/11, jp = r - 11*i;
      const float* Zc = sZ[mt][cur];
      const float* Yc = sY[mt][cur];
      v2f acc = (v2f)(0.f);
      #pragma unroll
      for (int k = 0; k < 22; ++k)
        acc += *(const v2f*)(Yc + k*22 + 2*jp) * Zc[i*22 + k];
      v2f tv;
      tv.x = ((2*jp     == i) ? 3.f : 0.f) - acc.x;
      tv.y = ((2*jp + 1 == i) ? 3.f : 0.f) - acc.y;
      *(v2f*)(sT[mt] + i*22 + 2*jp) = tv;
    }
    __syncthreads();
    // Ynew = 0.5*Y@T ; Znew = 0.5*T@Z  (968 v2f elements)
    for (int idx = tid; idx < 968; idx += 256) {
      const int sel = idx/242, r = idx - 242*sel, i = r/11, jp = r - 11*i;
      const int mt = sel >> 1; const bool isZ = sel & 1;
      const float* A = isZ ? sT[mt] : sY[mt][cur];
      const float* B = isZ ? sZ[mt][cur] : sT[mt];
      v2f acc = (v2f)(0.f);
      #pragma unroll
      for (int k = 0; k < 22; ++k)
        acc += *(const v2f*)(B + k*22 + 2*jp) * A[i*22 + k];
      *(v2f*)((isZ ? sZ[mt][cur^1] : sY[mt][cur^1]) + i*22 + 2*jp) = 0.5f*acc;
    }
    __syncthreads();
    cur ^= 1;   // data now lives in buffer 'cur'
  }

  // phase D: S = sqrt(c_bn/c_rm)*Z_rm@Y_bn ; U = W1@W2 ; raw G (coalesced)
  {
    const float scale = sqrtf(sC[0]/sC[1]);
    const float* Zrm = sZ[1][cur];
    const float* Ybn = sY[0][cur];
    for (int idx = tid; idx < 484; idx += 256) {
      const int i = idx/22, j = idx - 22*i;
      float s = 0.f;
      for (int k = 0; k < 22; ++k) s += Zrm[i*22+k]*Ybn[k*22+j];
      sS[idx] = scale*s;
    }
  }
  for (int idx = tid; idx < 704; idx += 256) {
    const int n = idx/22, j = idx - 22*n;
    float s = 0.f;
    for (int k = 0; k < 32; ++k) s += sW1[n*32+k]*sW2[k*22+j];
    sU[idx] = s;
  }
  // raw G, coalesced: thread t owns v2f element r = 2t,2t+1 of all 4 outputs.
  if (tid < 242) {
    const int wi = h/9, bi = h - 9*wi;
    const float* base = conv_w + wi*4356 + bi*484 + 2*tid;
    v2f a0 = (v2f)(0.f), a1 = (v2f)(0.f), a2 = (v2f)(0.f), a3 = (v2f)(0.f);
    #pragma unroll
    for (int c = 0; c < 48; ++c) {
      const v2f wv2 = *(const v2f*)(base + c*13068);
      a0 += wv2*fc_w[c];
      a1 += wv2*fc_w[48+c];
      a2 += wv2*fc_w[96+c];
      a3 += wv2*fc_w[144+c];
    }
    *(v2f*)(sG +        2*tid) = a0;
    *(v2f*)(sG +  484 + 2*tid) = a1;
    *(v2f*)(sG +  968 + 2*tid) = a2;
    *(v2f*)(sG + 1452 + 2*tid) = a3;
  }
  __syncthreads();

  // V = U_top @ S: write transposed (Vt, packed) and row-major (stride 24)
  for (int idx = tid; idx < 484; idx += 256) {
    const int k = idx/22, j = idx - 22*k;
    float s = 0.f;
    for (int l = 0; l < 22; ++l) s += sU[k*22+l]*sS[l*22+j];
    ws[WS_VT + h*484 + j*22 + k] = s;
    ws[WS_V  + h*V_STRIDE + k*24 + j] = s;
  }
  // E = U_bot @ S (10x22)
  for (int idx = tid; idx < 220; idx += 256) {
    const int e = idx/22, j = idx - 22*e;
    float s = 0.f;
    for (int l = 0; l < 22; ++l) s += sU[(22+e)*22+l]*sS[l*22+j];
    sE[idx] = s;
  }
  __syncthreads();
  // D = E^T E (22x22, symmetric)
  for (int idx = tid; idx < 484; idx += 256) {
    const int i = idx/22, j = idx - 22*i;
    float s = 0.f;
    for (int e = 0; e < 10; ++e) s += sE[e*22+i]*sE[e*22+j];
    ws[WS_D + h*484 + idx] = s;
  }
  // G symmetrized into padded layout
  for (int idx = tid; idx < 1936; idx += 256) {
    const int o = idx/484, r = idx - 484*o, i = r/22, j = r - 22*i;
    const float v = 0.5f*(sG[o*484 + i*22 + j] + sG[o*484 + j*22 + i]);
    ws[WS_G + (o*27+h)*G_STRIDE + i*24 + j] = v;
  }
  if (h == 0 && tid < 4) {
    float s = 0.f;
    for (int c = 0; c < 48; ++c) s += fc_w[tid*48+c]*conv_b[c];
    ws[WS_CONST + tid] = s + fc_b[tid];
  }
}

// ---------------- main: P4 build + one-sided Jacobi + projection -----------
// h is wave-uniform -> V/D/G base pointers uniform -> scalar loads (SMEM).
// Zero LDS; 64-thread blocks (4 matrices) for even CU balance (R19: bigger
// blocks regressed; occupancy is grid-limited at 3.4 waves/SIMD).
__global__ void __launch_bounds__(64, 3) main_kernel(const float* __restrict__ x,
                                                     const float* __restrict__ ws,
                                                     float* __restrict__ out) {
  const int lane = threadIdx.x;
  const int g = lane >> 4, m = lane & 15;
  const int mm = (m < 10) ? m : 10;          // lanes 11..15 mirror pair 10 (inert)
  const int h  = blockIdx.x % 27;            // wave-uniform
  const int b  = (blockIdx.x/27)*4 + g;
  const int id = b*27 + h;                   // matrix index in x

  // V column pair 2mm, 2mm+1 (rows 2mm,2mm+1 of Vt; 44 contiguous floats)
  v2f vl[11], vrr[11];
  {
    const v2f* vb = (const v2f*)(ws + WS_VT + h*484 + mm*44);
    #pragma unroll
    for (int j = 0; j < 11; ++j) { vl[j] = vb[j]; vrr[j] = vb[11+j]; }
  }
  // init w = D rows 2mm, 2mm+1 (columns of symmetric D)
  v2f wl[11], wr[11];
  {
    const v2f* d2 = (const v2f*)(ws + WS_D + h*484 + mm*44);
    #pragma unroll
    for (int j = 0; j < 11; ++j) { wl[j] = d2[j]; wr[j] = d2[11+j]; }
  }
  // streamed build: for each row k, t_k = <Xrow_k, v>, then w += V[k][:] * t_k
  {
    const v2f* X2 = (const v2f*)(x + (size_t)id * 484);
    const float* Vrow = ws + WS_V + h*V_STRIDE;
    #pragma unroll 2
    for (int k = 0; k < 22; ++k) {
      v2f aL = (v2f)(0.f), aR = (v2f)(0.f);
      #pragma unroll
      for (int c = 0; c < 11; ++c) {
        v2f xv = X2[11*k + c];
        aL += xv*vl[c];
        aR += xv*vrr[c];
      }
      float tLk = aL.x + aL.y, tRk = aR.x + aR.y;
      const v2f* vk = (const v2f*)(Vrow + k*24);
      #pragma unroll
      for (int j = 0; j < 11; ++j) {
        v2f q = vk[j];
        wl[j] += q*tLk;
        wr[j] += q*tRk;
      }
    }
  }

  jacobi_sweeps(wl, wr, (m < 10), (m > 10), 2, 1e-4f);

  // log-eig coefficients: L = sum_j (log lam_j / lam_j^2) w_j w_j^T, lam^2 = ||w||^2
  float nL, nR;
  {
    v2f na = (v2f)(0.f), nb = (v2f)(0.f);
    #pragma unroll
    for (int i = 0; i < 11; ++i) { na += wl[i]*wl[i]; nb += wr[i]*wr[i]; }
    nL = na.x + na.y; nR = nb.x + nb.y;
  }
  const float HALF_LN2 = 0.34657359f;        // 0.5*ln(2)
  float coefL = HALF_LN2*log2f(fmaxf(nL, 1e-8f))*__builtin_amdgcn_rcpf(nL);
  float coefR = HALF_LN2*log2f(fmaxf(nR, 1e-8f))*__builtin_amdgcn_rcpf(nR);

  // projection: out[b,o] += sum_cols coef * (w^T G[o,h] w)
  #pragma unroll 1
  for (int o = 0; o < 4; ++o) {
    const float* Gptr = ws + WS_G + (o*27+h)*G_STRIDE;
    float qL = 0.f, qR = 0.f;
    #pragma unroll
    for (int k = 0; k < 22; ++k) {
      const v2f* g2 = (const v2f*)(Gptr + k*24);
      v2f sa = (v2f)(0.f), ra = (v2f)(0.f);
      #pragma unroll
      for (int j = 0; j < 11; ++j) {
        v2f q = g2[j];
        sa += q*wl[j];
        ra += q*wr[j];
      }
      float wLk = wl[k>>1][k&1], wRk = wr[k>>1][k&1];
      qL += wLk*(sa.x + sa.y);
      qR += wRk*(ra.x + ra.y);
    }
    float v = (m <= 10) ? (coefL*qL + coefR*qR) : 0.0f;
    v += __shfl_down(v, 8, 16);
    v += __shfl_down(v, 4, 16);
    v += __shfl_down(v, 2, 16);
    v += __shfl_down(v, 1, 16);
    if (m == 0) {
      if (h == 0) v += ws[WS_CONST + o];
      atomicAdd(out + b*4 + o, v);
    }
  }
}

extern "C" void kernel_launch(void* const* d_in, const int* in_sizes, int n_in,
                              void* d_out, int out_size, void* d_ws, size_t ws_size,
                              hipStream_t stream) {
  const float* x   = (const float*)d_in[0];
  const float* W1  = (const float*)d_in[1];
  const float* W2  = (const float*)d_in[2];
  const float* rm  = (const float*)d_in[3];
  const float* bn  = (const float*)d_in[4];
  const float* cw  = (const float*)d_in[5];
  const float* cb  = (const float*)d_in[6];
  const float* fw  = (const float*)d_in[7];
  const float* fb  = (const float*)d_in[8];
  float* out = (float*)d_out;
  float* ws  = (float*)d_ws;

  prep_kernel<<<27, 256, 0, stream>>>(rm, bn, W1, W2, cw, fw, cb, fb, ws, out);
  main_kernel<<<3456, 64, 0, stream>>>(x, ws, out);
}